// Round 2
// 30353.732 us; speedup vs baseline: 1.1492x; 1.1492x over previous
//
#include <hip/hip_runtime.h>
#include <cstdint>
#include <cstddef>

// ---------------------------------------------------------------------------
// GCN(2 conv) -> 2-layer LSTM (seq=20000, H=128) -> edge head.
// LSTM restructured: layer-2 pipelined one step behind layer-1 so each step is
// ONE phase (48 MFMAs/wave) + ONE raw barrier (no vmcnt drain). Each wave owns
// 16 h-columns x all 4 gates; gate math fully in-register across all 8 waves.
// gx input prefetched per-step from a gate-interleaved G layout [T][128][4].
// ---------------------------------------------------------------------------

typedef __attribute__((ext_vector_type(8))) short short8x;
typedef __attribute__((ext_vector_type(4))) float f32x4;
typedef __attribute__((ext_vector_type(4))) unsigned short ushort4x;

static __device__ __forceinline__ unsigned short f2bf(float x) {
  union { float f; unsigned u; } v; v.f = x;
  unsigned r = (v.u + 0x7fffu + ((v.u >> 16) & 1u)) >> 16;   // RNE
  return (unsigned short)r;
}
static __device__ __forceinline__ float bf2f(unsigned short s) {
  union { unsigned u; float f; } v; v.u = ((unsigned)s) << 16; return v.f;
}
static __device__ __forceinline__ float sigm(float x) {
  return __fdividef(1.f, 1.f + __expf(-x));
}
static __device__ __forceinline__ float tanh_(float x) {
  float e = __expf(2.f * x);            // inf-safe: e=inf -> 1, e=0 -> -1
  return 1.f - __fdividef(2.f, e + 1.f);
}

// ---------------------------------------------------------------------------
// degree / normalization
// ---------------------------------------------------------------------------
__global__ __launch_bounds__(256) void k_deg(const int* __restrict__ ei,
                                             int* __restrict__ deg, int E) {
  int e = blockIdx.x * 256 + threadIdx.x;
  if (e < E) atomicAdd(&deg[ei[E + e]], 1);
}

__global__ __launch_bounds__(256) void k_dinv(const int* __restrict__ deg,
                                              float* __restrict__ dinv, int n) {
  int i = blockIdx.x * 256 + threadIdx.x;
  if (i < n) dinv[i] = rsqrtf((float)(deg[i] + 1));   // +1 self-loop, deg>=1
}

// ---------------------------------------------------------------------------
// generic f32 GEMM: C[M,N] = A[M,128] @ B(128,N), K=128 fixed.
// bnmajor=0: B stored [128][N]; =1: B stored [N][128] (C = A @ B^T).
// obf16: store C bf16 AND gate-interleave columns: out col = (n&127)*4+(n>>7)
// (so the LSTM reads its 4 gate inputs for one h-col as a single 8B load).
// ---------------------------------------------------------------------------
__global__ __launch_bounds__(256) void k_gemm(
    const float* __restrict__ A, const float* __restrict__ B, void* __restrict__ C,
    int M, int N, int bnmajor, const float* __restrict__ bias0,
    const float* __restrict__ bias1, int obf16) {
  __shared__ float As[32][128];
  __shared__ float Bs[128][68];          // pad 68: bank = (4k+n)%32, conflict-free
  const int t  = threadIdx.x;
  const int m0 = blockIdx.x * 32;
  const int n0 = blockIdx.y * 64;

  for (int i = t; i < 1024; i += 256) {  // 32 rows x 32 float4
    int r = i >> 5, c4 = i & 31;
    *(float4*)&As[r][c4 * 4] = *(const float4*)(A + (size_t)(m0 + r) * 128 + c4 * 4);
  }
  if (!bnmajor) {
    for (int i = t; i < 2048; i += 256) { // 128 rows x 16 float4 (64 cols)
      int r = i >> 4, c4 = i & 15;
      float4 v = *(const float4*)(B + (size_t)r * N + n0 + c4 * 4);
      *(float4*)&Bs[r][c4 * 4] = v;
    }
  } else {
    for (int i = t; i < 2048; i += 256) { // 64 rows x 32 float4 along k, transpose
      int n = i >> 5, k4 = i & 31;
      float4 v = *(const float4*)(B + (size_t)(n0 + n) * 128 + k4 * 4);
      Bs[k4 * 4 + 0][n] = v.x; Bs[k4 * 4 + 1][n] = v.y;
      Bs[k4 * 4 + 2][n] = v.z; Bs[k4 * 4 + 3][n] = v.w;
    }
  }
  __syncthreads();

  const int nl = t & 31, mg = t >> 5;    // 32 n-lanes x 8 m-groups(4 rows)
  float acc[4][2] = {};
  for (int k = 0; k < 128; ++k) {
    float b0 = Bs[k][nl], b1 = Bs[k][nl + 32];
    float a0 = As[mg * 4 + 0][k], a1 = As[mg * 4 + 1][k];
    float a2 = As[mg * 4 + 2][k], a3 = As[mg * 4 + 3][k];
    acc[0][0] += a0 * b0; acc[0][1] += a0 * b1;
    acc[1][0] += a1 * b0; acc[1][1] += a1 * b1;
    acc[2][0] += a2 * b0; acc[2][1] += a2 * b1;
    acc[3][0] += a3 * b0; acc[3][1] += a3 * b1;
  }
  float bv0 = 0.f, bv1 = 0.f;
  if (bias0) { bv0 += bias0[n0 + nl]; bv1 += bias0[n0 + nl + 32]; }
  if (bias1) { bv0 += bias1[n0 + nl]; bv1 += bias1[n0 + nl + 32]; }
  const int c0i = n0 + nl, c1i = n0 + nl + 32;
  const int p0i = ((c0i & 127) << 2) | (c0i >> 7);   // gate-interleaved col
  const int p1i = ((c1i & 127) << 2) | (c1i >> 7);
#pragma unroll
  for (int i = 0; i < 4; ++i) {
    size_t row = (size_t)(m0 + mg * 4 + i) * N;
    float v0 = acc[i][0] + bv0, v1 = acc[i][1] + bv1;
    if (obf16) {
      ((unsigned short*)C)[row + p0i] = f2bf(v0);
      ((unsigned short*)C)[row + p1i] = f2bf(v1);
    } else {
      ((float*)C)[row + c0i] = v0;
      ((float*)C)[row + c1i] = v1;
    }
  }
}

// ---------------------------------------------------------------------------
// y *= dinv[row] (in place) and acc = y  (self-loop init: out = dinv*(sum+y)+b)
// ---------------------------------------------------------------------------
__global__ __launch_bounds__(256) void k_scaleinit(float* __restrict__ y,
                                                   float* __restrict__ acc,
                                                   const float* __restrict__ dinv,
                                                   int total4) {
  int i = blockIdx.x * 256 + threadIdx.x;
  if (i >= total4) return;
  float s = dinv[i >> 5];
  float4 v = ((const float4*)y)[i];
  v.x *= s; v.y *= s; v.z *= s; v.w *= s;
  ((float4*)y)[i] = v;
  ((float4*)acc)[i] = v;
}

// acc[dst] += y[src], 32 threads (x float4) per edge
__global__ __launch_bounds__(256) void k_scatter(const float* __restrict__ y,
                                                 float* __restrict__ acc,
                                                 const int* __restrict__ ei, int E) {
  int g = blockIdx.x * 256 + threadIdx.x;
  int e = g >> 5, q = g & 31;
  if (e >= E) return;
  int s = ei[e], d = ei[E + e];
  float4 v = *(const float4*)(y + (size_t)s * 128 + q * 4);
  float* p = acc + (size_t)d * 128 + q * 4;
  atomicAdd(p + 0, v.x); atomicAdd(p + 1, v.y);
  atomicAdd(p + 2, v.z); atomicAdd(p + 3, v.w);
}

// out = (relu?)(dinv[row]*acc + bias)
__global__ __launch_bounds__(256) void k_finish(const float* __restrict__ acc,
                                                float* __restrict__ outb,
                                                const float* __restrict__ dinv,
                                                const float* __restrict__ bias,
                                                int total4, int relu) {
  int i = blockIdx.x * 256 + threadIdx.x;
  if (i >= total4) return;
  float s = dinv[i >> 5];
  float4 v = ((const float4*)acc)[i];
  float4 b = *(const float4*)(bias + (i & 31) * 4);
  v.x = v.x * s + b.x; v.y = v.y * s + b.y;
  v.z = v.z * s + b.z; v.w = v.w * s + b.w;
  if (relu) {
    v.x = fmaxf(v.x, 0.f); v.y = fmaxf(v.y, 0.f);
    v.z = fmaxf(v.z, 0.f); v.w = fmaxf(v.w, 0.f);
  }
  ((float4*)outb)[i] = v;
}

// ---------------------------------------------------------------------------
// Fused 2-layer LSTM scan, layer-2 pipelined one step behind layer-1.
// One workgroup, 512 threads (8 waves, 2/SIMD). Wave w owns h-cols
// [16w,16w+16); per step each wave runs 48 MFMAs (g1: K=128, g2: K=256 over
// [h0;h1]) and computes all 4 gate nonlinearities for its cols in-register.
// State double-buffered in LDS by t&1 -> exactly ONE raw barrier per step
// (lgkmcnt-only: gx prefetch loads and hs1 stores stay in flight).
//   iteration t: h0[t] = L1(h0[t-1], gx[t]);  h1[t-1] = L2(h0[t-1], h1[t-2])
// G layout: [T][128][4] bf16 (gate-interleaved), one 8B load/lane/step,
// prefetched one step ahead (G is L3-resident).
// ---------------------------------------------------------------------------
#define MFMA16(a, b, c) __builtin_amdgcn_mfma_f32_16x16x32_bf16((a), (b), (c), 0, 0, 0)

__global__ __launch_bounds__(512, 2) void k_lstm(
    const unsigned short* __restrict__ G,
    const float* __restrict__ whh0, const float* __restrict__ wih1,
    const float* __restrict__ whh1, const float* __restrict__ bih1,
    const float* __restrict__ bhh1, float* __restrict__ hs1,
    float* __restrict__ hncn, int T) {
  __shared__ __align__(16) unsigned short h0buf[2][128];   // bf16 h layer 1
  __shared__ __align__(16) unsigned short h1buf[2][128];   // bf16 h layer 2

  const int tid  = threadIdx.x;
  const int lane = tid & 63;
  const int wave = tid >> 6;       // 0..7
  const int col  = lane & 15;
  const int kg   = lane >> 4;      // k-group-of-8 within 32-k tile
  const int myc  = wave * 16 + col;  // owned h index 0..127 (4 lanes/col redundant)

  // --- weight B-fragments (bf16): B[gate][kt], reg j = W[gate*128+myc][k0+j]
  // B1: whh0 (K=128).  B2[kt<4]: wih1;  B2[kt>=4]: whh1  (merged K=256).
  short8x B1[4][4], B2[4][8];
#pragma unroll
  for (int g = 0; g < 4; ++g) {
    const float* p0 = whh0 + (size_t)(g * 128 + myc) * 128 + kg * 8;
    const float* p1 = wih1 + (size_t)(g * 128 + myc) * 128 + kg * 8;
    const float* p2 = whh1 + (size_t)(g * 128 + myc) * 128 + kg * 8;
#pragma unroll
    for (int kt = 0; kt < 4; ++kt) {
      short8x v0, v1, v2;
#pragma unroll
      for (int j = 0; j < 8; ++j) {
        v0[j] = (short)f2bf(p0[kt * 32 + j]);
        v1[j] = (short)f2bf(p1[kt * 32 + j]);
        v2[j] = (short)f2bf(p2[kt * 32 + j]);
      }
      B1[g][kt] = v0; B2[g][kt] = v1; B2[g][kt + 4] = v2;
    }
  }
  const float b2i = bih1[myc]       + bhh1[myc];
  const float b2f = bih1[myc + 128] + bhh1[myc + 128];
  const float b2g = bih1[myc + 256] + bhh1[myc + 256];
  const float b2o = bih1[myc + 384] + bhh1[myc + 384];

  if (tid < 128) {
    h0buf[0][tid] = 0; h0buf[1][tid] = 0;
    h1buf[0][tid] = 0; h1buf[1][tid] = 0;
  }
  float c0 = 0.f, c1 = 0.f, h0f = 0.f, h1f = 0.f;

  // prefetch gx[0]
  ushort4x gxn = *(const ushort4x*)(G + (size_t)0 * 512 + myc * 4);
  __syncthreads();

  for (int t = 0; t <= T; ++t) {
    const int p = t & 1;

    ushort4x gxc = gxn;
    {
      int tn = t + 1; if (tn >= T) tn = T - 1;       // clamped, branchless
      gxn = *(const ushort4x*)(G + (size_t)tn * 512 + myc * 4);
    }

    f32x4 z = {0.f, 0.f, 0.f, 0.f};
    f32x4 a1i = z, a1f = z, a1g = z, a1o = z;   // layer-1 gate chains
    f32x4 a2i = z, a2f = z, a2g = z, a2o = z;   // layer-2 gate chains
#pragma unroll
    for (int kt = 0; kt < 4; ++kt) {            // h0[t-1] feeds g1 and g2-lower
      short8x a = *(const short8x*)(&h0buf[p][kt * 32 + kg * 8]);
      a1i = MFMA16(a, B1[0][kt], a1i);
      a1f = MFMA16(a, B1[1][kt], a1f);
      a1g = MFMA16(a, B1[2][kt], a1g);
      a1o = MFMA16(a, B1[3][kt], a1o);
      a2i = MFMA16(a, B2[0][kt], a2i);
      a2f = MFMA16(a, B2[1][kt], a2f);
      a2g = MFMA16(a, B2[2][kt], a2g);
      a2o = MFMA16(a, B2[3][kt], a2o);
    }
#pragma unroll
    for (int kt = 0; kt < 4; ++kt) {            // h1[t-2] feeds g2-upper
      short8x a = *(const short8x*)(&h1buf[p][kt * 32 + kg * 8]);
      a2i = MFMA16(a, B2[0][kt + 4], a2i);
      a2f = MFMA16(a, B2[1][kt + 4], a2f);
      a2g = MFMA16(a, B2[2][kt + 4], a2g);
      a2o = MFMA16(a, B2[3][kt + 4], a2o);
    }

    if (t < T) {                                // layer-1 gates -> h0[t]
      float gi = bf2f(gxc[0]) + a1i[0];
      float gf = bf2f(gxc[1]) + a1f[0];
      float gg = bf2f(gxc[2]) + a1g[0];
      float go = bf2f(gxc[3]) + a1o[0];
      c0 = sigm(gf) * c0 + sigm(gi) * tanh_(gg);
      h0f = sigm(go) * tanh_(c0);
      if (lane < 16) h0buf[p ^ 1][myc] = f2bf(h0f);
    }
    if (t > 0) {                                // layer-2 gates -> h1[t-1]
      float gi = a2i[0] + b2i;
      float gf = a2f[0] + b2f;
      float gg = a2g[0] + b2g;
      float go = a2o[0] + b2o;
      c1 = sigm(gf) * c1 + sigm(gi) * tanh_(gg);
      h1f = sigm(go) * tanh_(c1);
      if (lane < 16) {
        h1buf[p ^ 1][myc] = f2bf(h1f);
        hs1[(size_t)(t - 1) * 128 + myc] = h1f;  // fire-and-forget
      }
    }

    // ds_writes visible to all waves; vmcnt deliberately NOT drained
    asm volatile("s_waitcnt lgkmcnt(0)" ::: "memory");
    __builtin_amdgcn_s_barrier();
    asm volatile("" ::: "memory");
  }

  if (lane < 16) {                 // hn = [h0T, h1T], cn = [c0T, c1T]
    hncn[myc]       = h0f;
    hncn[128 + myc] = h1f;
    hncn[256 + myc] = c0;
    hncn[384 + myc] = c1;
  }
}

// ---------------------------------------------------------------------------
// edge head: src/dst gather-writes, edge_emb = ef@eW+eb, pred = combined.cW+cb
// one wave per edge iteration; lane l owns components {2l,2l+1} / emb {l,l+64}
// ---------------------------------------------------------------------------
__global__ __launch_bounds__(256) void k_edge(
    const float* __restrict__ S, const int* __restrict__ ei,
    const float* __restrict__ ef, const float* __restrict__ eW,
    const float* __restrict__ eb, const float* __restrict__ cW,
    const float* __restrict__ cb, float* __restrict__ out, int E) {
  const int lane = threadIdx.x & 63;
  const int gw   = (blockIdx.x * 256 + threadIdx.x) >> 6;
  const int nw   = gridDim.x * 4;
  const size_t so = (size_t)E + 512;                  // src rows offset
  const size_t doff = so + (size_t)E * 128;           // dst rows offset

  const float cs0 = cW[2 * lane], cs1 = cW[2 * lane + 1];
  const float cd0 = cW[128 + 2 * lane], cd1 = cW[128 + 2 * lane + 1];
  const float ce0 = cW[256 + lane], ce1 = cW[320 + lane];
  const float eb0 = eb[lane], eb1 = eb[lane + 64];
  const float cbv = cb[0];

  for (int e = gw; e < E; e += nw) {
    int s = ei[e], d = ei[E + e];
    float2 vs = *(const float2*)(S + (size_t)s * 128 + 2 * lane);
    float2 vd = *(const float2*)(S + (size_t)d * 128 + 2 * lane);
    *(float2*)(out + so + (size_t)e * 128 + 2 * lane) = vs;
    *(float2*)(out + doff + (size_t)e * 128 + 2 * lane) = vd;

    float a0 = eb0, a1 = eb1;
    const float* efr = ef + (size_t)e * 32;
#pragma unroll
    for (int k = 0; k < 32; ++k) {
      float x = efr[k];
      a0 += x * eW[k * 128 + lane];
      a1 += x * eW[k * 128 + 64 + lane];
    }
    float p = vs.x * cs0 + vs.y * cs1 + vd.x * cd0 + vd.y * cd1 + a0 * ce0 + a1 * ce1;
#pragma unroll
    for (int m = 32; m; m >>= 1) p += __shfl_xor(p, m, 64);
    if (lane == 0) out[e] = p + cbv;
  }
}

// ---------------------------------------------------------------------------
extern "C" void kernel_launch(void* const* d_in, const int* in_sizes, int n_in,
                              void* d_out, int out_size, void* d_ws, size_t ws_size,
                              hipStream_t stream) {
  const float* x    = (const float*)d_in[0];
  const int*   ei   = (const int*)d_in[1];
  const float* ef   = (const float*)d_in[2];
  const float* W1   = (const float*)d_in[3];
  const float* b1   = (const float*)d_in[4];
  const float* W2   = (const float*)d_in[5];
  const float* b2   = (const float*)d_in[6];
  const float* wih0 = (const float*)d_in[7];
  const float* whh0 = (const float*)d_in[8];
  const float* bih0 = (const float*)d_in[9];
  const float* bhh0 = (const float*)d_in[10];
  const float* wih1 = (const float*)d_in[11];
  const float* whh1 = (const float*)d_in[12];
  const float* bih1 = (const float*)d_in[13];
  const float* bhh1 = (const float*)d_in[14];
  const float* eW   = (const float*)d_in[15];
  const float* eb   = (const float*)d_in[16];
  const float* cW   = (const float*)d_in[17];
  const float* cb   = (const float*)d_in[18];

  const int nN = in_sizes[0] / 128;   // 20000
  const int E  = in_sizes[1] / 2;     // 320000

  char* ws = (char*)d_ws;
  float* dinv          = (float*)ws;                       //  80 KB slot
  int*   deg           = (int*)(ws + 81920);               //  80 KB slot
  float* buf1          = (float*)(ws + 163840);            // [nN,128]
  float* buf2          = buf1 + (size_t)nN * 128;          // [nN,128]
  float* buf3          = buf2 + (size_t)nN * 128;          // [nN,128]
  unsigned short* G    = (unsigned short*)(buf3 + (size_t)nN * 128); // [nN,512] bf16
  float* S             = (float*)(G + (size_t)nN * 512);   // [nN,128] hs1
  float* out           = (float*)d_out;

  const int total4 = nN * 32;
  const int gElem  = (total4 + 255) / 256;
  const dim3 g128(nN / 32, 2);   // N=128 GEMMs
  const dim3 g512(nN / 32, 8);   // N=512 GEMM

  // degree / normalization
  hipMemsetAsync(deg, 0, nN * sizeof(int), stream);
  k_deg<<<(E + 255) / 256, 256, 0, stream>>>(ei, deg, E);
  k_dinv<<<(nN + 255) / 256, 256, 0, stream>>>(deg, dinv, nN);

  // conv1: h = relu(dinv*(scatter(x@W1 * dinv)) + b1)
  k_gemm<<<g128, 256, 0, stream>>>(x, W1, buf1, nN, 128, 0, nullptr, nullptr, 0);
  k_scaleinit<<<gElem, 256, 0, stream>>>(buf1, buf2, dinv, total4);
  k_scatter<<<(E * 32 + 255) / 256, 256, 0, stream>>>(buf1, buf2, ei, E);
  k_finish<<<gElem, 256, 0, stream>>>(buf2, buf3, dinv, b1, total4, 1);

  // conv2 (no relu)
  k_gemm<<<g128, 256, 0, stream>>>(buf3, W2, buf1, nN, 128, 0, nullptr, nullptr, 0);
  k_scaleinit<<<gElem, 256, 0, stream>>>(buf1, buf2, dinv, total4);
  k_scatter<<<(E * 32 + 255) / 256, 256, 0, stream>>>(buf1, buf2, ei, E);
  k_finish<<<gElem, 256, 0, stream>>>(buf2, buf3, dinv, b2, total4, 0);

  // gx0 = h2 @ wih0^T + (bih0 + bhh0), stored bf16 gate-interleaved [T][128][4]
  k_gemm<<<g512, 256, 0, stream>>>(buf3, wih0, G, nN, 512, 1, bih0, bhh0, 1);

  // fused 2-layer LSTM scan (single workgroup); hn/cn written into d_out
  k_lstm<<<1, 512, 0, stream>>>(G, whh0, wih1, whh1, bih1, bhh1, S, out + (size_t)E, nN);

  // edge head
  k_edge<<<2048, 256, 0, stream>>>(S, ei, ef, eW, eb, cW, cb, out, E);
}